// Round 1
// baseline (754.369 us; speedup 1.0000x reference)
//
#include <hip/hip_runtime.h>
#include <hip/hip_bf16.h>
#include <stdint.h>

#define D_DIM 2048
#define N_ROWS 16384
#define NE 8

using f32x4  = __attribute__((ext_vector_type(4))) float;
using bf16x8 = __attribute__((ext_vector_type(8))) __bf16;
using us8    = __attribute__((ext_vector_type(8))) unsigned short;

__device__ __forceinline__ unsigned short bf16_trunc(float f) {
    return (unsigned short)(__float_as_uint(f) >> 16);
}
__device__ __forceinline__ float bf16_hi_f32(float f) {
    return __uint_as_float(__float_as_uint(f) & 0xffff0000u);
}

// ---------------------------------------------------------------------------
// Kernel 1: gate for row 0 only (reference indexes top_k[0]). 1 wave.
// Writes to ws: [0]=w0 [1]=w1 (floats), [2]=i0 [3]=i1 (ints, aliased).
// ---------------------------------------------------------------------------
__global__ void gate_kernel(const float* __restrict__ x,
                            const float* __restrict__ Wg,
                            const float* __restrict__ bg,
                            float* __restrict__ ws) {
    const int lane = threadIdx.x;  // 0..63
    float p[NE];
#pragma unroll
    for (int e = 0; e < NE; ++e) p[e] = 0.f;
    for (int d = lane; d < D_DIM; d += 64) {
        const float xv = x[d];
#pragma unroll
        for (int e = 0; e < NE; ++e) p[e] += xv * Wg[e * D_DIM + d];
    }
#pragma unroll
    for (int e = 0; e < NE; ++e) {
#pragma unroll
        for (int off = 32; off > 0; off >>= 1)
            p[e] += __shfl_down(p[e], off, 64);
    }
    if (lane == 0) {
        float logits[NE], pr[NE];
        float m = -1e30f;
        for (int e = 0; e < NE; ++e) { logits[e] = p[e] + bg[e]; m = fmaxf(m, logits[e]); }
        float s = 0.f;
        for (int e = 0; e < NE; ++e) { pr[e] = expf(logits[e] - m); s += pr[e]; }
        const float inv = 1.0f / s;
        for (int e = 0; e < NE; ++e) pr[e] *= inv;
        int i0 = 0;
        for (int e = 1; e < NE; ++e) if (pr[e] > pr[i0]) i0 = e;
        int i1 = (i0 == 0) ? 1 : 0;
        for (int e = 0; e < NE; ++e) if (e != i0 && pr[e] > pr[i1]) i1 = e;
        ws[0] = pr[i0];
        ws[1] = pr[i1];
        ((int*)ws)[2] = i0;
        ((int*)ws)[3] = i1;
    }
}

// ---------------------------------------------------------------------------
// Kernel 2: W_eff = w0*We[i0] + w1*We[i1], split into bf16 hi/lo planes.
// 2048 blocks x 256 threads x 8 elements.
// ---------------------------------------------------------------------------
__global__ void wsplit_kernel(const float* __restrict__ We,
                              const float* __restrict__ gate,
                              unsigned short* __restrict__ Whi,
                              unsigned short* __restrict__ Wlo) {
    const float w0 = gate[0], w1 = gate[1];
    const int i0 = ((const int*)gate)[2];
    const int i1 = ((const int*)gate)[3];
    const size_t base = ((size_t)blockIdx.x * 256 + threadIdx.x) * 8;
    const float* p0 = We + (size_t)i0 * D_DIM * D_DIM + base;
    const float* p1 = We + (size_t)i1 * D_DIM * D_DIM + base;
    const float4 a0 = *(const float4*)(p0);
    const float4 a1 = *(const float4*)(p0 + 4);
    const float4 b0 = *(const float4*)(p1);
    const float4 b1 = *(const float4*)(p1 + 4);
    float v[8];
    v[0] = w0 * a0.x + w1 * b0.x;  v[1] = w0 * a0.y + w1 * b0.y;
    v[2] = w0 * a0.z + w1 * b0.z;  v[3] = w0 * a0.w + w1 * b0.w;
    v[4] = w0 * a1.x + w1 * b1.x;  v[5] = w0 * a1.y + w1 * b1.y;
    v[6] = w0 * a1.z + w1 * b1.z;  v[7] = w0 * a1.w + w1 * b1.w;
    us8 hi, lo;
#pragma unroll
    for (int j = 0; j < 8; ++j) {
        const float f = v[j];
        hi[j] = bf16_trunc(f);
        lo[j] = bf16_trunc(f - bf16_hi_f32(f));
    }
    *(us8*)(Whi + base) = hi;
    *(us8*)(Wlo + base) = lo;
}

// ---------------------------------------------------------------------------
// Kernel 3: out = x @ W_eff^T + b_eff, bf16 hi/lo split GEMM.
// Tile 128x128, BK=64, 256 threads (4 waves, 2x2), mfma_f32_16x16x32_bf16.
// LDS XOR-swizzle: ushort idx ^ ((row&7)<<3)  (== byte ^ ((row&7)<<4)).
// ---------------------------------------------------------------------------
#define BM 128
#define BN 128
#define BK 64

__global__ __launch_bounds__(256, 2)
void gemm_kernel(const float* __restrict__ x,
                 const unsigned short* __restrict__ Whi,
                 const unsigned short* __restrict__ Wlo,
                 const float* __restrict__ be,
                 const float* __restrict__ gate,
                 float* __restrict__ out) {
    __shared__ __align__(16) unsigned short lds[4 * 8192];  // 64 KB
    unsigned short* As_hi = lds;
    unsigned short* As_lo = lds + 8192;
    unsigned short* Bs_hi = lds + 16384;
    unsigned short* Bs_lo = lds + 24576;

    const int tid  = threadIdx.x;
    const int lane = tid & 63;
    const int wid  = tid >> 6;
    const int wm   = wid >> 1;   // 0..1
    const int wn   = wid & 1;    // 0..1

    const int bid  = blockIdx.x;
    const int bm   = bid >> 4;   // 0..127
    const int bn   = bid & 15;   // 0..15
    const int brow = bm * BM;
    const int bcol = bn * BN;

    // staging coords: thread t owns row t/2, 32-elem segment (t&1)
    const int srow = tid >> 1;
    const int sseg = (tid & 1) * 32;
    const int ssw  = (srow & 7) << 3;
    const int sidx = srow * 64 + sseg;

    const float*          xrow  = x   + (size_t)(brow + srow) * D_DIM;
    const unsigned short* whrow = Whi + (size_t)(bcol + srow) * D_DIM;
    const unsigned short* wlrow = Wlo + (size_t)(bcol + srow) * D_DIM;

    f32x4 acc[4][4];
#pragma unroll
    for (int m = 0; m < 4; ++m)
#pragma unroll
        for (int n = 0; n < 4; ++n) acc[m][n] = (f32x4){0.f, 0.f, 0.f, 0.f};

    for (int kt = 0; kt < D_DIM / BK; ++kt) {
        const int k0 = kt * BK;
        // ---- stage A (x): fp32 -> hi/lo bf16, swizzled ds_write_b128 ----
#pragma unroll
        for (int c = 0; c < 4; ++c) {
            const float4 u = *(const float4*)(xrow + k0 + sseg + c * 8);
            const float4 v = *(const float4*)(xrow + k0 + sseg + c * 8 + 4);
            float vals[8];
            vals[0] = u.x; vals[1] = u.y; vals[2] = u.z; vals[3] = u.w;
            vals[4] = v.x; vals[5] = v.y; vals[6] = v.z; vals[7] = v.w;
            us8 hi, lo;
#pragma unroll
            for (int j = 0; j < 8; ++j) {
                const float f = vals[j];
                hi[j] = bf16_trunc(f);
                lo[j] = bf16_trunc(f - bf16_hi_f32(f));
            }
            const int idx = (sidx + c * 8) ^ ssw;
            *(us8*)(As_hi + idx) = hi;
            *(us8*)(As_lo + idx) = lo;
        }
        // ---- stage B (pre-split Whi/Wlo): straight us8 copy, swizzled ----
#pragma unroll
        for (int c = 0; c < 4; ++c) {
            const us8 h = *(const us8*)(whrow + k0 + sseg + c * 8);
            const us8 l = *(const us8*)(wlrow + k0 + sseg + c * 8);
            const int idx = (sidx + c * 8) ^ ssw;
            *(us8*)(Bs_hi + idx) = h;
            *(us8*)(Bs_lo + idx) = l;
        }
        __syncthreads();
        // ---- compute: 2 k-slices x 4x4 frags x 3 split terms ----
#pragma unroll
        for (int kk = 0; kk < 2; ++kk) {
            const int kc = kk * 32 + (lane >> 4) * 8;
            bf16x8 ah[4], al[4], bh[4], bl[4];
#pragma unroll
            for (int m = 0; m < 4; ++m) {
                const int r   = wm * 64 + m * 16 + (lane & 15);
                const int idx = (r * 64 + kc) ^ ((r & 7) << 3);
                ah[m] = __builtin_bit_cast(bf16x8, *(const us8*)(As_hi + idx));
                al[m] = __builtin_bit_cast(bf16x8, *(const us8*)(As_lo + idx));
            }
#pragma unroll
            for (int n = 0; n < 4; ++n) {
                const int r   = wn * 64 + n * 16 + (lane & 15);
                const int idx = (r * 64 + kc) ^ ((r & 7) << 3);
                bh[n] = __builtin_bit_cast(bf16x8, *(const us8*)(Bs_hi + idx));
                bl[n] = __builtin_bit_cast(bf16x8, *(const us8*)(Bs_lo + idx));
            }
#pragma unroll
            for (int m = 0; m < 4; ++m)
#pragma unroll
                for (int n = 0; n < 4; ++n) {
                    acc[m][n] = __builtin_amdgcn_mfma_f32_16x16x32_bf16(ah[m], bh[n], acc[m][n], 0, 0, 0);
                    acc[m][n] = __builtin_amdgcn_mfma_f32_16x16x32_bf16(ah[m], bl[n], acc[m][n], 0, 0, 0);
                    acc[m][n] = __builtin_amdgcn_mfma_f32_16x16x32_bf16(al[m], bh[n], acc[m][n], 0, 0, 0);
                }
        }
        __syncthreads();
    }

    // ---- epilogue: bias + store (C frag: row=(lane>>4)*4+r, col=lane&15) ----
    const float w0 = gate[0], w1 = gate[1];
    const int i0 = ((const int*)gate)[2];
    const int i1 = ((const int*)gate)[3];
#pragma unroll
    for (int n = 0; n < 4; ++n) {
        const int gcol = bcol + wn * 64 + n * 16 + (lane & 15);
        const float bias = w0 * be[i0 * D_DIM + gcol] + w1 * be[i1 * D_DIM + gcol];
#pragma unroll
        for (int m = 0; m < 4; ++m) {
            const int growb = brow + wm * 64 + m * 16 + ((lane >> 4) << 2);
#pragma unroll
            for (int r = 0; r < 4; ++r) {
                out[(size_t)(growb + r) * D_DIM + gcol] = acc[m][n][r] + bias;
            }
        }
    }
}

// ---------------------------------------------------------------------------
extern "C" void kernel_launch(void* const* d_in, const int* in_sizes, int n_in,
                              void* d_out, int out_size, void* d_ws, size_t ws_size,
                              hipStream_t stream) {
    const float* x  = (const float*)d_in[0];
    const float* Wg = (const float*)d_in[1];
    const float* bg = (const float*)d_in[2];
    const float* We = (const float*)d_in[3];
    const float* be = (const float*)d_in[4];
    float* out = (float*)d_out;

    float* gate_ws = (float*)d_ws;
    unsigned short* Whi = (unsigned short*)((char*)d_ws + 256);
    unsigned short* Wlo = (unsigned short*)((char*)d_ws + 256 + (size_t)D_DIM * D_DIM * 2);

    gate_kernel<<<1, 64, 0, stream>>>(x, Wg, bg, gate_ws);
    wsplit_kernel<<<(D_DIM * D_DIM) / (256 * 8), 256, 0, stream>>>(We, gate_ws, Whi, Wlo);
    gemm_kernel<<<(N_ROWS / BM) * (D_DIM / BN), 256, 0, stream>>>(x, Whi, Wlo, be, gate_ws, out);
}

// Round 2
// 458.103 us; speedup vs baseline: 1.6467x; 1.6467x over previous
//
#include <hip/hip_runtime.h>
#include <hip/hip_bf16.h>
#include <stdint.h>

#define D_DIM 2048
#define N_ROWS 16384
#define NE 8

#define BM 128
#define BN 128
#define BK 64

using f32x4 = __attribute__((ext_vector_type(4))) float;
using f16x8 = __attribute__((ext_vector_type(8))) _Float16;
using us8   = __attribute__((ext_vector_type(8))) unsigned short;

__device__ __forceinline__ unsigned short f2h(float f) {
    return __builtin_bit_cast(unsigned short, (_Float16)f);  // RTN
}

// ---------------------------------------------------------------------------
// Kernel 1: gate for row 0 only (reference applies top_k[0] to whole batch).
// ws: [0]=w0 [1]=w1 (float), [2]=i0 [3]=i1 (int, aliased).
// ---------------------------------------------------------------------------
__global__ void gate_kernel(const float* __restrict__ x,
                            const float* __restrict__ Wg,
                            const float* __restrict__ bg,
                            float* __restrict__ ws) {
    const int lane = threadIdx.x;  // 0..63
    float p[NE];
#pragma unroll
    for (int e = 0; e < NE; ++e) p[e] = 0.f;
    for (int d = lane; d < D_DIM; d += 64) {
        const float xv = x[d];
#pragma unroll
        for (int e = 0; e < NE; ++e) p[e] += xv * Wg[e * D_DIM + d];
    }
#pragma unroll
    for (int e = 0; e < NE; ++e) {
#pragma unroll
        for (int off = 32; off > 0; off >>= 1)
            p[e] += __shfl_down(p[e], off, 64);
    }
    if (lane == 0) {
        float logits[NE], pr[NE];
        float m = -1e30f;
        for (int e = 0; e < NE; ++e) { logits[e] = p[e] + bg[e]; m = fmaxf(m, logits[e]); }
        float s = 0.f;
        for (int e = 0; e < NE; ++e) { pr[e] = expf(logits[e] - m); s += pr[e]; }
        const float inv = 1.0f / s;
        for (int e = 0; e < NE; ++e) pr[e] *= inv;
        int i0 = 0;
        for (int e = 1; e < NE; ++e) if (pr[e] > pr[i0]) i0 = e;
        int i1 = (i0 == 0) ? 1 : 0;
        for (int e = 0; e < NE; ++e) if (e != i0 && pr[e] > pr[i1]) i1 = e;
        ws[0] = pr[i0];
        ws[1] = pr[i1];
        ((int*)ws)[2] = i0;
        ((int*)ws)[3] = i1;
    }
}

// ---------------------------------------------------------------------------
// Kernel 2: W_eff = w0*We[i0] + w1*We[i1] -> fp16 (RTN). 8 MB out.
// ---------------------------------------------------------------------------
__global__ void wcvt_kernel(const float* __restrict__ We,
                            const float* __restrict__ gate,
                            unsigned short* __restrict__ Wh) {
    const float w0 = gate[0], w1 = gate[1];
    const int i0 = ((const int*)gate)[2];
    const int i1 = ((const int*)gate)[3];
    const size_t base = ((size_t)blockIdx.x * 256 + threadIdx.x) * 8;
    const float* p0 = We + (size_t)i0 * D_DIM * D_DIM + base;
    const float* p1 = We + (size_t)i1 * D_DIM * D_DIM + base;
    const float4 a0 = *(const float4*)(p0);
    const float4 a1 = *(const float4*)(p0 + 4);
    const float4 b0 = *(const float4*)(p1);
    const float4 b1 = *(const float4*)(p1 + 4);
    us8 h;
    h[0] = f2h(w0 * a0.x + w1 * b0.x);  h[1] = f2h(w0 * a0.y + w1 * b0.y);
    h[2] = f2h(w0 * a0.z + w1 * b0.z);  h[3] = f2h(w0 * a0.w + w1 * b0.w);
    h[4] = f2h(w0 * a1.x + w1 * b1.x);  h[5] = f2h(w0 * a1.y + w1 * b1.y);
    h[6] = f2h(w0 * a1.z + w1 * b1.z);  h[7] = f2h(w0 * a1.w + w1 * b1.w);
    *(us8*)(Wh + base) = h;
}

// ---------------------------------------------------------------------------
// Kernel 3: x -> fp16 (RTN). 67 MB out.
// ---------------------------------------------------------------------------
__global__ void xcvt_kernel(const float* __restrict__ x,
                            unsigned short* __restrict__ xh) {
    const size_t base = ((size_t)blockIdx.x * 256 + threadIdx.x) * 8;
    const float4 a = *(const float4*)(x + base);
    const float4 b = *(const float4*)(x + base + 4);
    us8 h;
    h[0] = f2h(a.x); h[1] = f2h(a.y); h[2] = f2h(a.z); h[3] = f2h(a.w);
    h[4] = f2h(b.x); h[5] = f2h(b.y); h[6] = f2h(b.z); h[7] = f2h(b.w);
    *(us8*)(xh + base) = h;
}

// ---------------------------------------------------------------------------
// Kernel 4: out = x @ W_eff^T + b_eff. fp16 single-plane, 128x128 tile,
// BK=64, 4 waves (2x2), mfma_f32_16x16x32_f16, linear LDS,
// global_load_lds width-16 staging, bijective XCD swizzle.
// ---------------------------------------------------------------------------
template <bool PRE>
__global__ __launch_bounds__(256, 3)
void gemm_f16(const float* __restrict__ x,
              const unsigned short* __restrict__ xh,
              const unsigned short* __restrict__ wh,
              const float* __restrict__ be,
              const float* __restrict__ gate,
              float* __restrict__ out) {
    __shared__ __align__(16) unsigned short As[BM * BK];  // [row][k], 16 kB
    __shared__ __align__(16) unsigned short Bs[BN * BK];  // [row][k], 16 kB

    const int tid  = threadIdx.x;
    const int lane = tid & 63;
    const int wid  = tid >> 6;
    const int wm   = wid >> 1;   // 0..1
    const int wn   = wid & 1;    // 0..1

    // bijective XCD swizzle (nwg = 2048, divisible by 8)
    const int cpx  = ((N_ROWS / BM) * (D_DIM / BN)) >> 3;  // 256
    const int swz  = (blockIdx.x & 7) * cpx + (blockIdx.x >> 3);
    const int bm   = swz >> 4;   // 0..127
    const int bn   = swz & 15;   // 0..15
    const int brow = bm * BM;
    const int bcol = bn * BN;

    // global_load_lds staging coords: issue r covers rows [r*32, r*32+32)
    // lane l -> row r*32 + wid*8 + (l>>3), k elems [(l&7)*8, +8)
    const int srow = wid * 8 + (lane >> 3);
    const int skel = (lane & 7) * 8;

    // fallback (reg-stage) coords: thread t -> row t/2, 32-elem seg (t&1)*32
    const int frow = tid >> 1;
    const int fseg = (tid & 1) * 32;

    f32x4 acc[4][4];
#pragma unroll
    for (int m = 0; m < 4; ++m)
#pragma unroll
        for (int n = 0; n < 4; ++n) acc[m][n] = (f32x4){0.f, 0.f, 0.f, 0.f};

    for (int kt = 0; kt < D_DIM / BK; ++kt) {
        const int k0 = kt * BK;
        __syncthreads();  // previous compute done before overwrite
        // ---- stage B (always pre-converted fp16) ----
#if __has_builtin(__builtin_amdgcn_global_load_lds)
#pragma unroll
        for (int r = 0; r < 4; ++r) {
            const unsigned short* g =
                wh + (size_t)(bcol + r * 32 + srow) * D_DIM + k0 + skel;
            unsigned short* l = Bs + r * 2048 + wid * 512;  // wave-uniform base
            __builtin_amdgcn_global_load_lds(
                (const __attribute__((address_space(1))) void*)g,
                (__attribute__((address_space(3))) void*)l, 16, 0, 0);
        }
#else
#pragma unroll
        for (int c = 0; c < 4; ++c) {
            const us8 h = *(const us8*)(wh + (size_t)(bcol + frow) * D_DIM + k0 + fseg + c * 8);
            *(us8*)(Bs + frow * 64 + fseg + c * 8) = h;
        }
#endif
        // ---- stage A ----
        if (PRE) {
#if __has_builtin(__builtin_amdgcn_global_load_lds)
#pragma unroll
            for (int r = 0; r < 4; ++r) {
                const unsigned short* g =
                    xh + (size_t)(brow + r * 32 + srow) * D_DIM + k0 + skel;
                unsigned short* l = As + r * 2048 + wid * 512;
                __builtin_amdgcn_global_load_lds(
                    (const __attribute__((address_space(1))) void*)g,
                    (__attribute__((address_space(3))) void*)l, 16, 0, 0);
            }
#else
#pragma unroll
            for (int c = 0; c < 4; ++c) {
                const us8 h = *(const us8*)(xh + (size_t)(brow + frow) * D_DIM + k0 + fseg + c * 8);
                *(us8*)(As + frow * 64 + fseg + c * 8) = h;
            }
#endif
        } else {
            const float* xr = x + (size_t)(brow + frow) * D_DIM;
#pragma unroll
            for (int c = 0; c < 4; ++c) {
                const float4 u = *(const float4*)(xr + k0 + fseg + c * 8);
                const float4 v = *(const float4*)(xr + k0 + fseg + c * 8 + 4);
                us8 h;
                h[0] = f2h(u.x); h[1] = f2h(u.y); h[2] = f2h(u.z); h[3] = f2h(u.w);
                h[4] = f2h(v.x); h[5] = f2h(v.y); h[6] = f2h(v.z); h[7] = f2h(v.w);
                *(us8*)(As + frow * 64 + fseg + c * 8) = h;
            }
        }
        __syncthreads();  // drains vmcnt (global_load_lds) + lgkmcnt
        // ---- compute: 2 k-slices x (4+4 ds_read_b128) x 16 MFMA ----
#pragma unroll
        for (int kk = 0; kk < 2; ++kk) {
            const int kc = kk * 32 + (lane >> 4) * 8;
            f16x8 a[4], b[4];
#pragma unroll
            for (int m = 0; m < 4; ++m) {
                const int r = wm * 64 + m * 16 + (lane & 15);
                a[m] = __builtin_bit_cast(f16x8, *(const us8*)(As + r * 64 + kc));
            }
#pragma unroll
            for (int n = 0; n < 4; ++n) {
                const int r = wn * 64 + n * 16 + (lane & 15);
                b[n] = __builtin_bit_cast(f16x8, *(const us8*)(Bs + r * 64 + kc));
            }
#pragma unroll
            for (int m = 0; m < 4; ++m)
#pragma unroll
                for (int n = 0; n < 4; ++n)
                    acc[m][n] = __builtin_amdgcn_mfma_f32_16x16x32_f16(a[m], b[n], acc[m][n], 0, 0, 0);
        }
    }

    // ---- epilogue: bias + store (C frag: row=(lane>>4)*4+r, col=lane&15) ----
    const float w0 = gate[0], w1 = gate[1];
    const int i0 = ((const int*)gate)[2];
    const int i1 = ((const int*)gate)[3];
#pragma unroll
    for (int n = 0; n < 4; ++n) {
        const int gcol = bcol + wn * 64 + n * 16 + (lane & 15);
        const float bias = w0 * be[i0 * D_DIM + gcol] + w1 * be[i1 * D_DIM + gcol];
#pragma unroll
        for (int m = 0; m < 4; ++m) {
            const int growb = brow + wm * 64 + m * 16 + ((lane >> 4) << 2);
#pragma unroll
            for (int r = 0; r < 4; ++r) {
                out[(size_t)(growb + r) * D_DIM + gcol] = acc[m][n][r] + bias;
            }
        }
    }
}

// ---------------------------------------------------------------------------
extern "C" void kernel_launch(void* const* d_in, const int* in_sizes, int n_in,
                              void* d_out, int out_size, void* d_ws, size_t ws_size,
                              hipStream_t stream) {
    const float* x  = (const float*)d_in[0];
    const float* Wg = (const float*)d_in[1];
    const float* bg = (const float*)d_in[2];
    const float* We = (const float*)d_in[3];
    const float* be = (const float*)d_in[4];
    float* out = (float*)d_out;

    float* gate_ws = (float*)d_ws;
    unsigned short* Wh = (unsigned short*)((char*)d_ws + 256);
    const size_t whBytes = (size_t)D_DIM * D_DIM * 2;              // 8 MB
    unsigned short* Xh = (unsigned short*)((char*)d_ws + 256 + whBytes);
    const size_t xhBytes = (size_t)N_ROWS * D_DIM * 2;             // 67 MB
    const bool pre = ws_size >= 256 + whBytes + xhBytes;

    gate_kernel<<<1, 64, 0, stream>>>(x, Wg, bg, gate_ws);
    wcvt_kernel<<<(D_DIM * D_DIM) / (256 * 8), 256, 0, stream>>>(We, gate_ws, Wh);
    const int ngrid = (N_ROWS / BM) * (D_DIM / BN);  // 2048
    if (pre) {
        xcvt_kernel<<<(N_ROWS * D_DIM) / (256 * 8), 256, 0, stream>>>(x, Xh);
        gemm_f16<true><<<ngrid, 256, 0, stream>>>(x, Xh, Wh, be, gate_ws, out);
    } else {
        gemm_f16<false><<<ngrid, 256, 0, stream>>>(x, nullptr, Wh, be, gate_ws, out);
    }
}